// Round 4
// baseline (203.966 us; speedup 1.0000x reference)
//
#include <hip/hip_runtime.h>

// Problem constants (fixed by the reference file)
#define SEQ   3456
#define DH    32
#define FPT   216        // feats_per_t
#define NT    16         // SEQ/FPT
#define IMG0  20         // first img feature index (FPT-196)
#define SCALE 0.17677669529663687f   // 1/sqrt(32)

// Visibility (verified rounds 1-3):
//  same-t: all keys visible except img->img => all queries see j<20;
//          non-img queries (qm<20) also see j=20..215 (phase B)
//  past d=1..7: only j<20; j==4 masked; joint queries (4<=qm<20) see only j<4.

// Phase-A K/V rows are WAVE-UNIFORM addresses -> compiler should emit s_load
// (scalar pipe), freeing the LDS/VMEM vector pipes that bound round 3.
__global__ __launch_bounds__(256)
void eye_attn_fused(const float* __restrict__ q, const float* __restrict__ k,
                    const float* __restrict__ v, float* __restrict__ out) {
    const int t   = blockIdx.x;
    const int bh  = blockIdx.y;
    const int tid = threadIdx.x;
    const size_t base = (size_t)bh * SEQ * DH;
    const int dmax = (t < 7) ? t : 7;

    __shared__ float part[240 * 33];   // phase-B partials only (31.7 KB)

    // ---- Phase A: thread = query (clamped; no divergent guard on loads) ----
    const int  qm      = tid;
    const bool activeA = qm < FPT;
    const int  qmc     = activeA ? qm : (FPT - 1);
    const bool qj      = (qmc >= 4) && (qmc < IMG0);

    float4 qr[8], acc[8];
    float  l = 0.f;
    {
        const float4* qp = (const float4*)(q + base + (size_t)(t * FPT + qmc) * DH);
        #pragma unroll
        for (int i = 0; i < 8; ++i) {
            float4 x = qp[i];
            x.x *= SCALE; x.y *= SCALE; x.z *= SCALE; x.w *= SCALE;
            qr[i] = x;
            acc[i] = make_float4(0.f, 0.f, 0.f, 0.f);
        }
    }
    const unsigned visPast = qj ? 0x0000Fu : 0xFFFEFu;  // 20-bit key mask
    for (int d = 0; d <= dmax; ++d) {
        const unsigned vm = (d == 0) ? 0xFFFFFu : visPast;
        const float* Kb = k + base + (size_t)((t - d) * FPT) * DH;  // uniform
        const float* Vb = v + base + (size_t)((t - d) * FPT) * DH;  // uniform
        #pragma unroll 2
        for (int j = 0; j < IMG0; ++j) {
            const float4* kr = (const float4*)(Kb + j * DH);  // uniform addr
            float s0 = 0.f, s1 = 0.f, s2 = 0.f, s3 = 0.f;
            #pragma unroll
            for (int i = 0; i < 8; ++i) {
                float4 kk = kr[i];
                s0 = fmaf(qr[i].x, kk.x, s0);
                s1 = fmaf(qr[i].y, kk.y, s1);
                s2 = fmaf(qr[i].z, kk.z, s2);
                s3 = fmaf(qr[i].w, kk.w, s3);
            }
            const float e = ((vm >> j) & 1u) ? __expf((s0 + s1) + (s2 + s3)) : 0.f;
            l += e;
            const float4* vr = (const float4*)(Vb + j * DH);  // uniform addr
            #pragma unroll
            for (int i = 0; i < 8; ++i) {
                float4 vv = vr[i];
                acc[i].x = fmaf(e, vv.x, acc[i].x);
                acc[i].y = fmaf(e, vv.y, acc[i].y);
                acc[i].z = fmaf(e, vv.z, acc[i].z);
                acc[i].w = fmaf(e, vv.w, acc[i].w);
            }
        }
    }

    // ---- Phase B: 20 non-img queries x 196 same-t img keys, 240 threads ----
    // thread tid = bq*12 + c; chunks 0..3 have 17 keys, 4..11 have 16.
    if (tid < 240) {
        const int bq = tid / 12;
        const int c  = tid - bq * 12;
        const int j0 = (c < 4) ? (IMG0 + c * 17) : (IMG0 + 68 + (c - 4) * 16);
        const int nj = (c < 4) ? 17 : 16;
        const float4* qp = (const float4*)(q + base + (size_t)(t * FPT + bq) * DH);
        float4 qb[8], ab[8];
        #pragma unroll
        for (int i = 0; i < 8; ++i) {
            float4 x = qp[i];
            x.x *= SCALE; x.y *= SCALE; x.z *= SCALE; x.w *= SCALE;
            qb[i] = x;
            ab[i] = make_float4(0.f, 0.f, 0.f, 0.f);
        }
        float lb = 0.f;
        for (int jj = 0; jj < nj; ++jj) {
            const size_t row = base + (size_t)(t * FPT + j0 + jj) * DH;
            const float4* kr = (const float4*)(k + row);
            float s0 = 0.f, s1 = 0.f, s2 = 0.f, s3 = 0.f;
            #pragma unroll
            for (int i = 0; i < 8; ++i) {
                float4 kk = kr[i];
                s0 = fmaf(qb[i].x, kk.x, s0);
                s1 = fmaf(qb[i].y, kk.y, s1);
                s2 = fmaf(qb[i].z, kk.z, s2);
                s3 = fmaf(qb[i].w, kk.w, s3);
            }
            const float e = __expf((s0 + s1) + (s2 + s3));
            lb += e;
            const float4* vr = (const float4*)(v + row);
            #pragma unroll
            for (int i = 0; i < 8; ++i) {
                float4 vv = vr[i];
                ab[i].x = fmaf(e, vv.x, ab[i].x);
                ab[i].y = fmaf(e, vv.y, ab[i].y);
                ab[i].z = fmaf(e, vv.z, ab[i].z);
                ab[i].w = fmaf(e, vv.w, ab[i].w);
            }
        }
        // partial -> LDS, stride 33 (conflict-free: gcd(33,32)=1)
        float* p = part + tid * 33;
        p[0] = lb;
        #pragma unroll
        for (int i = 0; i < 8; ++i) {
            p[1 + 4 * i] = ab[i].x; p[2 + 4 * i] = ab[i].y;
            p[3 + 4 * i] = ab[i].z; p[4 + 4 * i] = ab[i].w;
        }
    }
    __syncthreads();

    // ---- merge + normalize + store ----
    if (activeA) {
        if (qm < IMG0) {
            for (int c = 0; c < 12; ++c) {
                const float* p = part + (qm * 12 + c) * 33;
                l += p[0];
                #pragma unroll
                for (int i = 0; i < 8; ++i) {
                    acc[i].x += p[1 + 4 * i]; acc[i].y += p[2 + 4 * i];
                    acc[i].z += p[3 + 4 * i]; acc[i].w += p[4 + 4 * i];
                }
            }
        }
        const float inv = 1.f / l;
        float4* op = (float4*)(out + base + (size_t)(t * FPT + qm) * DH);
        #pragma unroll
        for (int i = 0; i < 8; ++i) {
            float4 r = acc[i];
            r.x *= inv; r.y *= inv; r.z *= inv; r.w *= inv;
            op[i] = r;
        }
    }
}

extern "C" void kernel_launch(void* const* d_in, const int* in_sizes, int n_in,
                              void* d_out, int out_size, void* d_ws, size_t ws_size,
                              hipStream_t stream) {
    const float* q = (const float*)d_in[0];
    const float* k = (const float*)d_in[1];
    const float* v = (const float*)d_in[2];
    float* out = (float*)d_out;
    const int BH = in_sizes[0] / (SEQ * DH);   // 24
    dim3 grid(NT, BH);
    eye_attn_fused<<<grid, 256, 0, stream>>>(q, k, v, out);
}

// Round 5
// 110.349 us; speedup vs baseline: 1.8484x; 1.8484x over previous
//
#include <hip/hip_runtime.h>

#define SEQ   3456
#define DH    32
#define FPT   216
#define NT    16
#define IMG0  20
#define SCALE 0.17677669529663687f

#define KPAD 40    // Ks row stride (bf16) - 80B: 2-way bank aliasing (free)
#define VPAD 168   // Vt row stride (bf16) - 336B
#define PPAD 36    // P  row stride (fp32) - 144B

typedef __attribute__((ext_vector_type(8))) short bf16x8;
typedef __attribute__((ext_vector_type(4))) float f32x4;

#define MFMA16(a,b,c) __builtin_amdgcn_mfma_f32_16x16x32_bf16(a,b,c,0,0,0)

__device__ __forceinline__ unsigned short bfh(float f) {      // fp32->bf16 RTNE
    unsigned u = __float_as_uint(f);
    u += 0x7FFFu + ((u >> 16) & 1u);
    return (unsigned short)(u >> 16);
}
__device__ __forceinline__ float bff(unsigned short h) {
    return __uint_as_float((unsigned)h << 16);
}
__device__ __forceinline__ void split8(const float* f, bf16x8& hi, bf16x8& lo) {
    #pragma unroll
    for (int j = 0; j < 8; ++j) {
        unsigned short h = bfh(f[j]);
        hi[j] = (short)h;
        lo[j] = (short)bfh(f[j] - bff(h));
    }
}

// Layouts (m89/m118/m120-verified):
//  A-frag 16x16x32: A[m = lane&15][k = (lane>>4)*8 + j]
//  B-frag:          B[k = (lane>>4)*8 + j][n = lane&15]
//  C/D:             D[row = (lane>>4)*4 + reg][col = lane&15]
__global__ __launch_bounds__(256)
void eye_attn_mfma(const float* __restrict__ q, const float* __restrict__ k,
                   const float* __restrict__ v, float* __restrict__ out) {
    __shared__ __align__(16) unsigned short KsHi[160 * KPAD];
    __shared__ __align__(16) unsigned short KsLo[160 * KPAD];
    __shared__ __align__(16) unsigned short VtHi[DH * VPAD];
    __shared__ __align__(16) unsigned short VtLo[DH * VPAD];
    __shared__ __align__(16) float Pl[4 * 16 * PPAD];

    const int t = blockIdx.x, bh = blockIdx.y, tid = threadIdx.x;
    const size_t base = (size_t)bh * SEQ * DH;
    const int dmax = (t < 7) ? t : 7;
    const int nkeys = IMG0 * (dmax + 1);   // staged small keys (g = d*20+jj)

    // ---- stage small K (rows, bf16 hi/lo) and V^T (transposed) ----
    for (int i = tid; i < 160 * 8; i += 256) {
        const int g = i >> 3, c = i & 7;
        float4 kk = make_float4(0.f,0.f,0.f,0.f), vv = make_float4(0.f,0.f,0.f,0.f);
        if (g < nkeys) {
            const int d = g / IMG0, jj = g - d * IMG0;
            const size_t row = base + (size_t)((t - d) * FPT + jj) * DH + c * 4;
            kk = *(const float4*)(k + row);
            vv = *(const float4*)(v + row);
        }
        const float kf[4] = {kk.x, kk.y, kk.z, kk.w};
        const float vf[4] = {vv.x, vv.y, vv.z, vv.w};
        ushort4 khi, klo;
        unsigned short* ah = (unsigned short*)&khi;
        unsigned short* al = (unsigned short*)&klo;
        #pragma unroll
        for (int e = 0; e < 4; ++e) {
            const unsigned short h = bfh(kf[e]);
            ah[e] = h;
            al[e] = bfh(kf[e] - bff(h));
        }
        *(ushort4*)(KsHi + g * KPAD + c * 4) = khi;
        *(ushort4*)(KsLo + g * KPAD + c * 4) = klo;
        #pragma unroll
        for (int e = 0; e < 4; ++e) {
            const unsigned short h = bfh(vf[e]);
            VtHi[(c * 4 + e) * VPAD + g] = h;
            VtLo[(c * 4 + e) * VPAD + g] = bfh(vf[e] - bff(h));
        }
    }
    __syncthreads();   // only barrier; Pl regions are wave-private below

    const int wv = tid >> 6, lane = tid & 63;
    const int col = lane & 15, quad = lane >> 4;

    // 14 M-tiles over 4 waves; img work (M-tiles 0,1) balances 3-vs-4 tiles
    int mtiles[4]; int mcnt;
    if (wv == 0)      { mtiles[0]=0;  mtiles[1]=2;  mtiles[2]=3;  mtiles[3]=0; mcnt=3; }
    else if (wv == 1) { mtiles[0]=1;  mtiles[1]=4;  mtiles[2]=5;  mtiles[3]=0; mcnt=3; }
    else if (wv == 2) { mtiles[0]=6;  mtiles[1]=7;  mtiles[2]=8;  mtiles[3]=9; mcnt=4; }
    else              { mtiles[0]=10; mtiles[1]=11; mtiles[2]=12; mtiles[3]=13; mcnt=4; }

    bf16x8 bones;   // B[k][0] = 1: row-sum via MFMA -> l lands in col 0
    #pragma unroll
    for (int j = 0; j < 8; ++j) bones[j] = (short)(col == 0 ? 0x3F80 : 0);

    float* myP = Pl + wv * 16 * PPAD;
    const int nkt = (nkeys + 31) >> 5;

    for (int mi = 0; mi < mcnt; ++mi) {
        const int mb = mtiles[mi] * 16;
        bf16x8 qhi, qlo;
        {
            const int qc = min(mb + col, FPT - 1);   // clamp; masked on store
            const float* qp = q + base + (size_t)(t * FPT + qc) * DH + quad * 8;
            float qf[8];
            const float4 a0 = *(const float4*)qp;
            const float4 a1 = *(const float4*)(qp + 4);
            qf[0]=a0.x*SCALE; qf[1]=a0.y*SCALE; qf[2]=a0.z*SCALE; qf[3]=a0.w*SCALE;
            qf[4]=a1.x*SCALE; qf[5]=a1.y*SCALE; qf[6]=a1.z*SCALE; qf[7]=a1.w*SCALE;
            split8(qf, qhi, qlo);
        }
        f32x4 oacc0 = {0.f,0.f,0.f,0.f}, oacc1 = {0.f,0.f,0.f,0.f};
        f32x4 lacc = {0.f,0.f,0.f,0.f};

        // ---- small keys: QK^T -> mask/exp -> P roundtrip -> PV + l ----
        for (int kt = 0; kt < nkt; ++kt) {
            f32x4 s[2];
            #pragma unroll
            for (int h = 0; h < 2; ++h) {
                const int key = kt * 32 + h * 16 + col;
                const bf16x8 bhi = *(const bf16x8*)(KsHi + key * KPAD + quad * 8);
                const bf16x8 blo = *(const bf16x8*)(KsLo + key * KPAD + quad * 8);
                f32x4 acc = {0.f,0.f,0.f,0.f};
                acc = MFMA16(qhi, bhi, acc);
                acc = MFMA16(qlo, bhi, acc);
                acc = MFMA16(qhi, blo, acc);
                s[h] = acc;
            }
            #pragma unroll
            for (int h = 0; h < 2; ++h) {
                const int g = kt * 32 + h * 16 + col;
                const int d = g / IMG0, jj = g - d * IMG0;
                #pragma unroll
                for (int r = 0; r < 4; ++r) {
                    const int qm = mb + quad * 4 + r;
                    const bool qj = (qm >= 4) && (qm < IMG0);
                    const bool vis = (g < nkeys) && (qm < FPT) &&
                                     ((d == 0) || ((jj != 4) && !(qj && jj >= 4)));
                    const float e = vis ? __expf(s[h][r]) : 0.f;
                    myP[(quad * 4 + r) * PPAD + h * 16 + col] = e;
                }
            }
            bf16x8 phi, plo;
            {
                const float* pr = myP + col * PPAD + quad * 8;
                float pf[8];
                const float4 p0 = *(const float4*)pr;
                const float4 p1 = *(const float4*)(pr + 4);
                pf[0]=p0.x; pf[1]=p0.y; pf[2]=p0.z; pf[3]=p0.w;
                pf[4]=p1.x; pf[5]=p1.y; pf[6]=p1.z; pf[7]=p1.w;
                split8(pf, phi, plo);
            }
            #pragma unroll
            for (int h = 0; h < 2; ++h) {
                const int dim = h * 16 + col;
                const bf16x8 vhi = *(const bf16x8*)(VtHi + dim * VPAD + kt * 32 + quad * 8);
                const bf16x8 vlo = *(const bf16x8*)(VtLo + dim * VPAD + kt * 32 + quad * 8);
                f32x4& oa = h ? oacc1 : oacc0;
                oa = MFMA16(phi, vhi, oa);
                oa = MFMA16(plo, vhi, oa);
                oa = MFMA16(phi, vlo, oa);
            }
            lacc = MFMA16(phi, bones, lacc);
            lacc = MFMA16(plo, bones, lacc);
        }

        // ---- same-t img keys (20..215): only queries < 20 (M-tiles 0,1) ----
        if (mi == 0 && wv < 2) {
            for (int kt2 = 0; kt2 < 7; ++kt2) {
                f32x4 s[2];
                #pragma unroll
                for (int h = 0; h < 2; ++h) {
                    const int keyc = min(IMG0 + kt2 * 32 + h * 16 + col, FPT - 1);
                    const float* kp = k + base + (size_t)(t * FPT + keyc) * DH + quad * 8;
                    float kf[8];
                    const float4 a0 = *(const float4*)kp;
                    const float4 a1 = *(const float4*)(kp + 4);
                    kf[0]=a0.x; kf[1]=a0.y; kf[2]=a0.z; kf[3]=a0.w;
                    kf[4]=a1.x; kf[5]=a1.y; kf[6]=a1.z; kf[7]=a1.w;
                    bf16x8 khi, klo;
                    split8(kf, khi, klo);
                    f32x4 acc = {0.f,0.f,0.f,0.f};
                    acc = MFMA16(qhi, khi, acc);
                    acc = MFMA16(qlo, khi, acc);
                    acc = MFMA16(qhi, klo, acc);
                    s[h] = acc;
                }
                #pragma unroll
                for (int h = 0; h < 2; ++h) {
                    const int key = IMG0 + kt2 * 32 + h * 16 + col;
                    #pragma unroll
                    for (int r = 0; r < 4; ++r) {
                        const int qm = mb + quad * 4 + r;
                        const bool vis = (key < FPT) && (qm < IMG0);
                        const float e = vis ? __expf(s[h][r]) : 0.f;
                        myP[(quad * 4 + r) * PPAD + h * 16 + col] = e;
                    }
                }
                bf16x8 phi, plo;
                {
                    const float* pr = myP + col * PPAD + quad * 8;
                    float pf[8];
                    const float4 p0 = *(const float4*)pr;
                    const float4 p1 = *(const float4*)(pr + 4);
                    pf[0]=p0.x; pf[1]=p0.y; pf[2]=p0.z; pf[3]=p0.w;
                    pf[4]=p1.x; pf[5]=p1.y; pf[6]=p1.z; pf[7]=p1.w;
                    split8(pf, phi, plo);
                }
                #pragma unroll
                for (int h = 0; h < 2; ++h) {
                    const int dim = h * 16 + col;
                    float vf[8];
                    #pragma unroll
                    for (int j = 0; j < 8; ++j) {
                        const int ky = min(IMG0 + kt2 * 32 + quad * 8 + j, FPT - 1);
                        vf[j] = v[base + (size_t)(t * FPT + ky) * DH + dim];
                    }
                    bf16x8 vhi, vlo;
                    split8(vf, vhi, vlo);
                    f32x4& oa = h ? oacc1 : oacc0;
                    oa = MFMA16(phi, vhi, oa);
                    oa = MFMA16(plo, vhi, oa);
                    oa = MFMA16(phi, vlo, oa);
                }
                lacc = MFMA16(phi, bones, lacc);
                lacc = MFMA16(plo, bones, lacc);
            }
        }

        // ---- epilogue: broadcast l (col 0 of quad), normalize, store ----
        #pragma unroll
        for (int r = 0; r < 4; ++r) {
            const float lr = __shfl(lacc[r], lane & 48);   // lane (quad*16 + 0)
            const float inv = 1.f / lr;
            const int qm = mb + quad * 4 + r;
            if (qm < FPT) {
                float* op = out + base + (size_t)(t * FPT + qm) * DH;
                op[col]      = oacc0[r] * inv;
                op[16 + col] = oacc1[r] * inv;
            }
        }
    }
}

extern "C" void kernel_launch(void* const* d_in, const int* in_sizes, int n_in,
                              void* d_out, int out_size, void* d_ws, size_t ws_size,
                              hipStream_t stream) {
    const float* q = (const float*)d_in[0];
    const float* k = (const float*)d_in[1];
    const float* v = (const float*)d_in[2];
    float* out = (float*)d_out;
    const int BH = in_sizes[0] / (SEQ * DH);   // 24
    dim3 grid(NT, BH);
    eye_attn_mfma<<<grid, 256, 0, stream>>>(q, k, v, out);
}

// Round 6
// 97.156 us; speedup vs baseline: 2.0994x; 1.1358x over previous
//
#include <hip/hip_runtime.h>

#define SEQ   3456
#define DH    32
#define FPT   216
#define NT    16
#define IMG0  20
#define SCALE 0.17677669529663687f

#define KPAD   40    // Ks row stride (u16): 80 B
#define VPAD   168   // Vt row stride (u16): 336 B
#define PPITCH 40    // P row stride (u16): 80 B, 16B-aligned b128 reads

typedef __attribute__((ext_vector_type(8))) short bf16x8;
typedef __attribute__((ext_vector_type(4))) float f32x4;

#define MFMA16(a,b,c) __builtin_amdgcn_mfma_f32_16x16x32_bf16(a,b,c,0,0,0)

__device__ __forceinline__ unsigned short bfh(float f) {      // fp32->bf16 RTNE
    unsigned u = __float_as_uint(f);
    u += 0x7FFFu + ((u >> 16) & 1u);
    return (unsigned short)(u >> 16);
}
__device__ __forceinline__ float bff(unsigned short h) {
    return __uint_as_float((unsigned)h << 16);
}
__device__ __forceinline__ void split8(const float* f, bf16x8& hi, bf16x8& lo) {
    #pragma unroll
    for (int j = 0; j < 8; ++j) {
        unsigned short h = bfh(f[j]);
        hi[j] = (short)h;
        lo[j] = (short)bfh(f[j] - bff(h));
    }
}

// Layouts (m89/m118/m120-verified):
//  A-frag 16x16x32: A[m = lane&15][k = (lane>>4)*8 + j]
//  B-frag:          B[k = (lane>>4)*8 + j][n = lane&15]
//  C/D:             D[row = (lane>>4)*4 + reg][col = lane&15]
// Accuracy design: QK uses 3-term bf16 compensation (score errors amplify
// through exp). PV/l use hi-only: P rounding cancels in the softmax ratio
// (l is summed from the same rounded P); V rounding ~0.4% rel.
__global__ __launch_bounds__(256)
void eye_attn_mfma2(const float* __restrict__ q, const float* __restrict__ k,
                    const float* __restrict__ v, float* __restrict__ out) {
    __shared__ __align__(16) unsigned short KsHi[160 * KPAD];   // 12.8 KB
    __shared__ __align__(16) unsigned short KsLo[160 * KPAD];   // 12.8 KB
    __shared__ __align__(16) unsigned short VtHi[DH * VPAD];    // 10.75 KB
    __shared__ __align__(16) unsigned short Pu[4 * 16 * PPITCH];// 5.1 KB

    const int t = blockIdx.x, bh = blockIdx.y, half = blockIdx.z;
    const int tid = threadIdx.x;
    const size_t base = (size_t)bh * SEQ * DH;
    const int dmax = (t < 7) ? t : 7;
    const int nkeys = IMG0 * (dmax + 1);     // staged small keys (g = d*20+jj)

    // ---- stage small K (hi/lo rows) and V^T (hi only), zero-padded ----
    for (int i = tid; i < 160 * 8; i += 256) {
        const int g = i >> 3, c = i & 7;
        float4 kk = make_float4(0.f,0.f,0.f,0.f), vv = make_float4(0.f,0.f,0.f,0.f);
        if (g < nkeys) {
            const int d = g / IMG0, jj = g - d * IMG0;
            const size_t row = base + (size_t)((t - d) * FPT + jj) * DH + c * 4;
            kk = *(const float4*)(k + row);
            vv = *(const float4*)(v + row);
        }
        const float kf[4] = {kk.x, kk.y, kk.z, kk.w};
        const float vf[4] = {vv.x, vv.y, vv.z, vv.w};
        ushort4 khi, klo;
        unsigned short* ah = (unsigned short*)&khi;
        unsigned short* al = (unsigned short*)&klo;
        #pragma unroll
        for (int e = 0; e < 4; ++e) {
            const unsigned short h = bfh(kf[e]);
            ah[e] = h;
            al[e] = bfh(kf[e] - bff(h));
        }
        *(ushort4*)(KsHi + g * KPAD + c * 4) = khi;
        *(ushort4*)(KsLo + g * KPAD + c * 4) = klo;
        #pragma unroll
        for (int e = 0; e < 4; ++e)
            VtHi[(c * 4 + e) * VPAD + g] = bfh(vf[e]);
    }
    __syncthreads();   // only barrier; Pu regions are wave-private below

    const int wv = tid >> 6, lane = tid & 63;
    const int col = lane & 15, quad = lane >> 4;

    // 14 M-tiles over 2 WGs x 4 waves; img work (tiles 0,1) goes to the
    // 1-tile waves of half 0: w0/w1 do 5+7=12 kt-units, others 10.
    int mt[2]; int mcnt; bool do_img = false;
    if (half == 0) {
        if (wv == 0)      { mt[0] = 0; mcnt = 1; do_img = true; }
        else if (wv == 1) { mt[0] = 1; mcnt = 1; do_img = true; }
        else if (wv == 2) { mt[0] = 2; mt[1] = 3; mcnt = 2; }
        else              { mt[0] = 4; mt[1] = 5; mcnt = 2; }
    } else {
        mt[0] = 6 + 2 * wv; mt[1] = 7 + 2 * wv; mcnt = 2;
    }

    bf16x8 bones;   // B[k][0] = 1: row-sum via MFMA -> l lands in col 0
    #pragma unroll
    for (int j = 0; j < 8; ++j) bones[j] = (short)(col == 0 ? 0x3F80 : 0);

    unsigned short* myP = Pu + wv * 16 * PPITCH;
    const int nkt = (nkeys + 31) >> 5;

    for (int mi = 0; mi < mcnt; ++mi) {
        const int mb = mt[mi] * 16;
        bf16x8 qhi, qlo;
        {
            const int qc = min(mb + col, FPT - 1);   // clamp; masked on store
            const float* qp = q + base + (size_t)(t * FPT + qc) * DH + quad * 8;
            float qf[8];
            const float4 a0 = *(const float4*)qp;
            const float4 a1 = *(const float4*)(qp + 4);
            qf[0]=a0.x*SCALE; qf[1]=a0.y*SCALE; qf[2]=a0.z*SCALE; qf[3]=a0.w*SCALE;
            qf[4]=a1.x*SCALE; qf[5]=a1.y*SCALE; qf[6]=a1.z*SCALE; qf[7]=a1.w*SCALE;
            split8(qf, qhi, qlo);
        }
        f32x4 oacc0 = {0.f,0.f,0.f,0.f}, oacc1 = {0.f,0.f,0.f,0.f};
        f32x4 lacc = {0.f,0.f,0.f,0.f};

        // ---- small keys: QK^T -> mask/exp -> P(bf16) roundtrip -> PV + l ----
        for (int kt = 0; kt < nkt; ++kt) {
            f32x4 s[2];
            #pragma unroll
            for (int h = 0; h < 2; ++h) {
                const int key = kt * 32 + h * 16 + col;
                const bf16x8 khi = *(const bf16x8*)(KsHi + key * KPAD + quad * 8);
                const bf16x8 klo = *(const bf16x8*)(KsLo + key * KPAD + quad * 8);
                f32x4 acc = {0.f,0.f,0.f,0.f};
                acc = MFMA16(qhi, khi, acc);
                acc = MFMA16(qlo, khi, acc);
                acc = MFMA16(qhi, klo, acc);
                s[h] = acc;
            }
            #pragma unroll
            for (int h = 0; h < 2; ++h) {
                const int g = kt * 32 + h * 16 + col;
                const int d = g / IMG0, jj = g - d * IMG0;
                #pragma unroll
                for (int r = 0; r < 4; ++r) {
                    const int qm = mb + quad * 4 + r;
                    const bool qj = (qm >= 4) && (qm < IMG0);
                    const bool vis = (g < nkeys) && (qm < FPT) &&
                                     ((d == 0) || ((jj != 4) && !(qj && jj >= 4)));
                    const float e = vis ? __expf(s[h][r]) : 0.f;
                    myP[(quad * 4 + r) * PPITCH + h * 16 + col] = bfh(e);
                }
            }
            const bf16x8 phi = *(const bf16x8*)(myP + col * PPITCH + quad * 8);
            #pragma unroll
            for (int h = 0; h < 2; ++h) {
                const int dim = h * 16 + col;
                const bf16x8 vhi = *(const bf16x8*)(VtHi + dim * VPAD + kt * 32 + quad * 8);
                f32x4& oa = h ? oacc1 : oacc0;
                oa = MFMA16(phi, vhi, oa);
            }
            lacc = MFMA16(phi, bones, lacc);
        }

        // ---- same-t img keys (20..215): only queries < 20 (M-tiles 0,1) ----
        if (mi == 0 && do_img) {
            for (int kt2 = 0; kt2 < 7; ++kt2) {
                f32x4 s[2];
                #pragma unroll
                for (int h = 0; h < 2; ++h) {
                    const int keyc = min(IMG0 + kt2 * 32 + h * 16 + col, FPT - 1);
                    const float* kp = k + base + (size_t)(t * FPT + keyc) * DH + quad * 8;
                    float kf[8];
                    const float4 a0 = *(const float4*)kp;
                    const float4 a1 = *(const float4*)(kp + 4);
                    kf[0]=a0.x; kf[1]=a0.y; kf[2]=a0.z; kf[3]=a0.w;
                    kf[4]=a1.x; kf[5]=a1.y; kf[6]=a1.z; kf[7]=a1.w;
                    bf16x8 khi, klo;
                    split8(kf, khi, klo);
                    f32x4 acc = {0.f,0.f,0.f,0.f};
                    acc = MFMA16(qhi, khi, acc);
                    acc = MFMA16(qlo, khi, acc);
                    acc = MFMA16(qhi, klo, acc);
                    s[h] = acc;
                }
                #pragma unroll
                for (int h = 0; h < 2; ++h) {
                    const int key = IMG0 + kt2 * 32 + h * 16 + col;
                    #pragma unroll
                    for (int r = 0; r < 4; ++r) {
                        const int qm = mb + quad * 4 + r;
                        const bool vis = (key < FPT) && (qm < IMG0);
                        const float e = vis ? __expf(s[h][r]) : 0.f;
                        myP[(quad * 4 + r) * PPITCH + h * 16 + col] = bfh(e);
                    }
                }
                const bf16x8 phi = *(const bf16x8*)(myP + col * PPITCH + quad * 8);
                #pragma unroll
                for (int h = 0; h < 2; ++h) {
                    const int dim = h * 16 + col;
                    float vf[8];
                    #pragma unroll
                    for (int j = 0; j < 8; ++j) {
                        const int ky = min(IMG0 + kt2 * 32 + quad * 8 + j, FPT - 1);
                        vf[j] = v[base + (size_t)(t * FPT + ky) * DH + dim];
                    }
                    bf16x8 vhi;
                    #pragma unroll
                    for (int j = 0; j < 8; ++j) vhi[j] = (short)bfh(vf[j]);
                    f32x4& oa = h ? oacc1 : oacc0;
                    oa = MFMA16(phi, vhi, oa);
                }
                lacc = MFMA16(phi, bones, lacc);
            }
        }

        // ---- epilogue: broadcast l (col 0 of quad), normalize, store ----
        #pragma unroll
        for (int r = 0; r < 4; ++r) {
            const float lr = __shfl(lacc[r], lane & 48);   // lane (quad*16 + 0)
            const float inv = 1.f / lr;
            const int qm = mb + quad * 4 + r;
            if (qm < FPT) {
                float* op = out + base + (size_t)(t * FPT + qm) * DH;
                op[col]      = oacc0[r] * inv;
                op[16 + col] = oacc1[r] * inv;
            }
        }
    }
}

extern "C" void kernel_launch(void* const* d_in, const int* in_sizes, int n_in,
                              void* d_out, int out_size, void* d_ws, size_t ws_size,
                              hipStream_t stream) {
    const float* q = (const float*)d_in[0];
    const float* k = (const float*)d_in[1];
    const float* v = (const float*)d_in[2];
    float* out = (float*)d_out;
    const int BH = in_sizes[0] / (SEQ * DH);   // 24
    dim3 grid(NT, BH, 2);                      // M-split: 768 WGs, 3/CU
    eye_attn_mfma2<<<grid, 256, 0, stream>>>(q, k, v, out);
}